// Round 11
// baseline (249.984 us; speedup 1.0000x reference)
//
#include <hip/hip_runtime.h>
#include <stdint.h>

typedef unsigned short u16;
typedef __bf16 bf16x8 __attribute__((ext_vector_type(8)));
typedef float f32x4 __attribute__((ext_vector_type(4)));

__device__ __forceinline__ u16 f2bf(float f) {
  union { float f; uint32_t u; } x; x.f = f;
  uint32_t u = x.u;
  u += 0x7fffu + ((u >> 16) & 1u);   // round-to-nearest-even
  return (u16)(u >> 16);
}
__device__ __forceinline__ float bf2f(uint32_t lo16) {
  union { uint32_t u; float f; } x; x.u = lo16 << 16; return x.f;
}
__device__ __forceinline__ float bfhi(uint32_t u) {
  union { uint32_t u; float f; } x; x.u = u & 0xffff0000u; return x.f;
}
// fix one bf16 pair: e_k = m_k + p_k * F_k, repacked to bf16x2
__device__ __forceinline__ uint32_t fixpair(uint32_t m, float p0, float p1,
                                            float F0, float F1) {
  float e0 = fmaf(p0, F0, bf2f(m & 0xffffu));
  float e1 = fmaf(p1, F1, bfhi(m));
  return (uint32_t)f2bf(e0) | ((uint32_t)f2bf(e1) << 16);
}

__device__ __forceinline__ void async_load16(const u16* g, u16* l) {
  __builtin_amdgcn_global_load_lds(
      (const __attribute__((address_space(1))) void*)g,
      (__attribute__((address_space(3))) void*)l,
      16, 0, 0);
}

// ---------------- prep_all: sigmoid(beta)+bpow table + weight/x converts ----------------
// bpow[p][h] = beta_h^p for p = 1..32 (fp32, 132 KB, L2-resident).
__global__ __launch_bounds__(256) void prep_all(const float* __restrict__ x,
                                                const float* __restrict__ Wq,
                                                const float* __restrict__ Wfc,
                                                const float* __restrict__ braw,
                                                u16* __restrict__ xb,
                                                u16* __restrict__ wqb,
                                                u16* __restrict__ wfcb,
                                                float* __restrict__ beta,
                                                float* __restrict__ bpow) {
  int gid = blockIdx.x * 256 + threadIdx.x;
  if (gid < 1024) {
    float b = 1.0f / (1.0f + expf(-braw[gid]));
    beta[gid] = b;
    float w = b;
#pragma unroll 1
    for (int p = 1; p <= 32; p++) { bpow[p * 1024 + gid] = w; w *= b; }
  }
  if (gid < 131072) {
    const int HH = 1024 * 1024;
    int i = gid * 16;
    const float* src = (i < HH) ? (Wq + i) : (Wfc + (i - HH));
    u16* dst = (i < HH) ? (wqb + i) : (wfcb + (i - HH));
#pragma unroll
    for (int c = 0; c < 4; c++) {
      float4 v = *(const float4*)(src + c * 4);
      ushort4 o = {f2bf(v.x), f2bf(v.y), f2bf(v.z), f2bf(v.w)};
      *(ushort4*)(dst + c * 4) = o;
    }
  }
  {
    int i = gid * 8;
    float4 a = *(const float4*)(x + i);
    float4 b = *(const float4*)(x + i + 4);
    ushort4 o0 = {f2bf(a.x), f2bf(a.y), f2bf(a.z), f2bf(a.w)};
    ushort4 o1 = {f2bf(b.x), f2bf(b.y), f2bf(b.z), f2bf(b.w)};
    *(ushort4*)(xb + i) = o0;
    *(ushort4*)(xb + i + 4) = o1;
  }
}

// ---------------- GEMM1 + fused segment-local scan: m_local = localscan(x Wq^T + b) ----
// Ring schedule = R1/R4 harness-verified (256x256 tile, BK=32, 4-deep LDS ring,
// counted vmcnt(8), XCD swizzle). Epilogue computes the FULL segment-local scan
// in-register and writes bf16 m_local + segment carry. Verified R7/R9/R10.
__global__ __launch_bounds__(512, 2) void gemm_scan(const u16* __restrict__ A,
                                                    const u16* __restrict__ B,
                                                    const float* __restrict__ bias,
                                                    u16* __restrict__ Cout,
                                                    const float* __restrict__ beta_arr,
                                                    float* __restrict__ carry_out,
                                                    int M, int N, int K) {
  __shared__ u16 lds[4][2][256 * 32];  // 128 KiB ring

  const int tid  = threadIdx.x;
  const int lane = tid & 63;
  const int wid  = tid >> 6;
  const int wr   = (wid >> 2) * 128;
  const int wc   = (wid & 3) * 64;

  const int bid    = blockIdx.x;
  const int xcd    = bid & 7;
  const int idx    = bid >> 3;
  const int tile_m = ((xcd << 3) | (idx >> 2)) * 256;
  const int tile_n = (idx & 3) * 256;

  const int srow    = tid >> 2;
  const int schunk  = (tid & 3) ^ ((srow >> 1) & 3);
  const u16* gA = A + (size_t)(tile_m + srow) * K + schunk * 8;
  const u16* gB = B + (size_t)(tile_n + srow) * K + schunk * 8;
  const size_t half_stride = (size_t)128 * K;

#define STAGE(slot, kt)                                                   \
  do {                                                                    \
    const size_t k0 = (size_t)(kt) * 32;                                  \
    async_load16(gA + k0,               &lds[slot][0][wid * 512]);        \
    async_load16(gA + k0 + half_stride, &lds[slot][0][4096 + wid * 512]); \
    async_load16(gB + k0,               &lds[slot][1][wid * 512]);        \
    async_load16(gB + k0 + half_stride, &lds[slot][1][4096 + wid * 512]); \
  } while (0)

  f32x4 acc[8][4];
#pragma unroll
  for (int i = 0; i < 8; i++)
#pragma unroll
    for (int j = 0; j < 4; j++) acc[i][j] = (f32x4){0.f, 0.f, 0.f, 0.f};

  const int lrow = lane & 15;
  const int kq   = lane >> 4;
  const int kc   = (lrow >> 1) & 3;
  const int coff = ((kq ^ kc) << 3);

  const int NKT = K >> 5;  // 32

  STAGE(0, 0);
  if (NKT > 1) STAGE(1, 1);
  if (NKT > 2) STAGE(2, 2);
  if (NKT > 2)      asm volatile("s_waitcnt vmcnt(8)" ::: "memory");
  else if (NKT > 1) asm volatile("s_waitcnt vmcnt(4)" ::: "memory");
  else              asm volatile("s_waitcnt vmcnt(0)" ::: "memory");
  __builtin_amdgcn_s_barrier();

  for (int kt = 0; kt < NKT; ++kt) {
    const int slot = kt & 3;
    const u16* As = &lds[slot][0][0];
    const u16* Bs = &lds[slot][1][0];

    bf16x8 a[8], b[4];
#pragma unroll
    for (int i = 0; i < 8; i++)
      a[i] = *(const bf16x8*)&As[(wr + i * 16 + lrow) * 32 + coff];
#pragma unroll
    for (int j = 0; j < 4; j++)
      b[j] = *(const bf16x8*)&Bs[(wc + j * 16 + lrow) * 32 + coff];

    if (kt + 3 < NKT) STAGE((kt + 3) & 3, kt + 3);

    __builtin_amdgcn_s_setprio(1);
#pragma unroll
    for (int i = 0; i < 8; i++)
#pragma unroll
      for (int j = 0; j < 4; j++)
        acc[i][j] = __builtin_amdgcn_mfma_f32_16x16x32_bf16(a[i], b[j], acc[i][j], 0, 0, 0);
    __builtin_amdgcn_s_setprio(0);

    const int ahead = NKT - 1 - kt;
    if (ahead >= 3) {
      asm volatile("s_waitcnt vmcnt(8)" ::: "memory");
      __builtin_amdgcn_s_barrier();
    } else if (ahead == 2) {
      asm volatile("s_waitcnt vmcnt(4)" ::: "memory");
      __builtin_amdgcn_s_barrier();
    } else if (ahead == 1) {
      asm volatile("s_waitcnt vmcnt(0)" ::: "memory");
      __builtin_amdgcn_s_barrier();
    }
  }
#undef STAGE

  // ---------------- fused segment-local scan epilogue ----------------
  const int crow = (lane >> 4) << 2;
  const int ccol = lane & 15;
  const int c4   = lane >> 4;
  const int kap  = c4 >> 1;
  const int Wh   = wr >> 7;
  float* sm15 = (float*)&lds[0][0][0];  // [8][256] fp32, 8 KB (ring slot 0)

  // Phase A: local (t-half) scan, in place in acc
#pragma unroll
  for (int j = 0; j < 4; j++) {
    const int gn = tile_n + wc + j * 16 + ccol;
    const float bv = bias[gn];
    const float be = beta_arr[gn];
    const float be2 = be * be;
#pragma unroll
    for (int r = 0; r < 4; r++) {
      float S[8], R[8];
      S[0] = acc[0][j][r] + bv;
#pragma unroll
      for (int i = 1; i < 8; i++) S[i] = fmaf(be2, S[i - 1], acc[i][j][r] + bv);
#pragma unroll
      for (int i = 0; i < 8; i++) R[i] = __shfl_xor(S[i], 32);
      acc[0][j][r] = kap ? fmaf(be, R[0], S[0]) : S[0];
#pragma unroll
      for (int i = 1; i < 8; i++)
        acc[i][j][r] = fmaf(be, kap ? R[i] : R[i - 1], S[i]);
    }
  }
  // Phase B: export m(15)
  if (Wh == 0 && kap == 1) {
#pragma unroll
    for (int j = 0; j < 4; j++)
#pragma unroll
      for (int r = 0; r < 4; r++) {
        const int bb = ((c4 << 2) + r) & 7;
        sm15[bb * 256 + wc + j * 16 + ccol] = acc[7][j][r];
      }
  }
  __syncthreads();
  // Phase C: upper half adds beta^{2i+kap+1} * m(15)
  if (Wh == 1) {
#pragma unroll
    for (int j = 0; j < 4; j++) {
      const int hl = wc + j * 16 + ccol;
      const float be = beta_arr[tile_n + hl];
      const float be2 = be * be;
#pragma unroll
      for (int r = 0; r < 4; r++) {
        const int bb = ((c4 << 2) + r) & 7;
        const float v = sm15[bb * 256 + hl];
        float f = kap ? be2 : be;
#pragma unroll
        for (int i = 0; i < 8; i++) {
          acc[i][j][r] = fmaf(f, v, acc[i][j][r]);
          f *= be2;
        }
      }
    }
  }
  // Phase D: store bf16 m_local (+ per-segment carry from registers)
#pragma unroll
  for (int i = 0; i < 8; i++) {
#pragma unroll
    for (int j = 0; j < 4; j++) {
      const int gm = tile_m + wr + i * 16 + crow;
      const int gn = tile_n + wc + j * 16 + ccol;
#pragma unroll
      for (int r = 0; r < 4; r++)
        Cout[(size_t)(gm + r) * N + gn] = f2bf(acc[i][j][r]);
    }
  }
  if (Wh == 1 && kap == 1) {
    const int seg = tile_m >> 8;
#pragma unroll
    for (int j = 0; j < 4; j++) {
      const int hl = wc + j * 16 + ccol;
#pragma unroll
      for (int r = 0; r < 4; r++) {
        const int bb = ((c4 << 2) + r) & 7;
        carry_out[(size_t)seg * 8192 + bb * 1024 + tile_n + hl] = acc[7][j][r];
      }
    }
  }
}

// ---------------- scanfix: ffold + mfix in ONE launch (saves a ~20us launch slot) ----
// Block (seg = bid>>5, part = bid&31) owns h-window [part*32, part*32+32) x all
// 8 b x all 32 t of one segment.
//   Phase 1 (fold): thread c (0..255) folds ONE channel (b = c>>5, hh = c&31):
//     F = sum_{s<seg} (beta_h^32)^(seg-1-s) carry[s][b][h]  -- loads coalesce in
//     128B/32-lane groups; fma chain short. Store to padded LDS [8][33] so the
//     stream phase's per-b reads land in distinct banks.
//   Phase 2 (stream): thread t handles row rl = t: tl = rl>>3, b = rl&7;
//     m = m_local + bpow[tl+1][h] * F[b][h], 64B in / 64B out per thread.
// seg=0: fold skipped, fixpair is an exact bf16 roundtrip (p*0 adds nothing).
// Blocks independent; carry is from the previous launch (stream-ordered).
__global__ __launch_bounds__(256) void scanfix(const u16* __restrict__ mloc,
                                               const float* __restrict__ carry,
                                               const float* __restrict__ bpow,
                                               u16* __restrict__ mout) {
  __shared__ float F_lds[8 * 33];

  const int tid  = threadIdx.x;
  const int seg  = blockIdx.x >> 5;
  const int part = blockIdx.x & 31;
  const int h0   = part * 32;

  // Phase 1: fold one channel per thread
  {
    const int fb = tid >> 5;          // b index 0..7
    const int hh = tid & 31;
    const int h  = h0 + hh;
    const float w = bpow[32 * 1024 + h];
    float F = 0.f;
    const float* cp = carry + fb * 1024 + h;
#pragma unroll 4
    for (int s = 0; s < seg; s++) F = fmaf(w, F, cp[(size_t)s * 8192]);
    F_lds[fb * 33 + hh] = F;
  }
  __syncthreads();

  // Phase 2: stream-fix one row per thread (32 bf16 = 4 uint4)
  {
    const int rl = tid;
    const int tl = rl >> 3;
    const int b  = rl & 7;
    const size_t row = (size_t)(seg * 256 + rl) * 1024 + h0;
    const uint4* mi = (const uint4*)(mloc + row);
    uint4*       mo = (uint4*)(mout + row);
    const float* p  = bpow + (size_t)(tl + 1) * 1024 + h0;
    const float* Fp = &F_lds[b * 33];
#pragma unroll
    for (int q = 0; q < 4; q++) {      // q covers h offsets 8q..8q+7
      const uint4 m = mi[q];
      const float4 p0 = *(const float4*)(p + q * 8);
      const float4 p1 = *(const float4*)(p + q * 8 + 4);
      const float4 f0 = *(const float4*)(Fp + q * 8);
      const float4 f1 = *(const float4*)(Fp + q * 8 + 4);
      uint4 o;
      o.x = fixpair(m.x, p0.x, p0.y, f0.x, f0.y);
      o.y = fixpair(m.y, p0.z, p0.w, f0.z, f0.w);
      o.z = fixpair(m.z, p1.x, p1.y, f1.x, f1.y);
      o.w = fixpair(m.w, p1.z, p1.w, f1.z, f1.w);
      mo[q] = o;
    }
  }
}

// ---------------- GEMM2: relu(m Wfc^T + b_fc), fp32 out ----------------
// Byte-identical schedule to R4/R10's measured ~46us ring.
__global__ __launch_bounds__(512, 2) void gemm_relu(const u16* __restrict__ A,
                                                    const u16* __restrict__ B,
                                                    const float* __restrict__ bias,
                                                    float* __restrict__ Cout,
                                                    int M, int N, int K) {
  __shared__ u16 lds[4][2][256 * 32];  // 128 KiB ring

  const int tid  = threadIdx.x;
  const int lane = tid & 63;
  const int wid  = tid >> 6;
  const int wr   = (wid >> 2) * 128;
  const int wc   = (wid & 3) * 64;

  const int bid    = blockIdx.x;
  const int xcd    = bid & 7;
  const int idx    = bid >> 3;
  const int tile_m = ((xcd << 3) | (idx >> 2)) * 256;
  const int tile_n = (idx & 3) * 256;

  const int srow    = tid >> 2;
  const int schunk  = (tid & 3) ^ ((srow >> 1) & 3);
  const u16* gA = A + (size_t)(tile_m + srow) * K + schunk * 8;
  const u16* gB = B + (size_t)(tile_n + srow) * K + schunk * 8;
  const size_t half_stride = (size_t)128 * K;

#define STAGE(slot, kt)                                                   \
  do {                                                                    \
    const size_t k0 = (size_t)(kt) * 32;                                  \
    async_load16(gA + k0,               &lds[slot][0][wid * 512]);        \
    async_load16(gA + k0 + half_stride, &lds[slot][0][4096 + wid * 512]); \
    async_load16(gB + k0,               &lds[slot][1][wid * 512]);        \
    async_load16(gB + k0 + half_stride, &lds[slot][1][4096 + wid * 512]); \
  } while (0)

  f32x4 acc[8][4];
#pragma unroll
  for (int i = 0; i < 8; i++)
#pragma unroll
    for (int j = 0; j < 4; j++) acc[i][j] = (f32x4){0.f, 0.f, 0.f, 0.f};

  const int lrow = lane & 15;
  const int kq   = lane >> 4;
  const int kc   = (lrow >> 1) & 3;
  const int coff = ((kq ^ kc) << 3);

  const int NKT = K >> 5;  // 32

  STAGE(0, 0);
  if (NKT > 1) STAGE(1, 1);
  if (NKT > 2) STAGE(2, 2);
  if (NKT > 2)      asm volatile("s_waitcnt vmcnt(8)" ::: "memory");
  else if (NKT > 1) asm volatile("s_waitcnt vmcnt(4)" ::: "memory");
  else              asm volatile("s_waitcnt vmcnt(0)" ::: "memory");
  __builtin_amdgcn_s_barrier();

  for (int kt = 0; kt < NKT; ++kt) {
    const int slot = kt & 3;
    const u16* As = &lds[slot][0][0];
    const u16* Bs = &lds[slot][1][0];

    bf16x8 a[8], b[4];
#pragma unroll
    for (int i = 0; i < 8; i++)
      a[i] = *(const bf16x8*)&As[(wr + i * 16 + lrow) * 32 + coff];
#pragma unroll
    for (int j = 0; j < 4; j++)
      b[j] = *(const bf16x8*)&Bs[(wc + j * 16 + lrow) * 32 + coff];

    if (kt + 3 < NKT) STAGE((kt + 3) & 3, kt + 3);

    __builtin_amdgcn_s_setprio(1);
#pragma unroll
    for (int i = 0; i < 8; i++)
#pragma unroll
      for (int j = 0; j < 4; j++)
        acc[i][j] = __builtin_amdgcn_mfma_f32_16x16x32_bf16(a[i], b[j], acc[i][j], 0, 0, 0);
    __builtin_amdgcn_s_setprio(0);

    const int ahead = NKT - 1 - kt;
    if (ahead >= 3) {
      asm volatile("s_waitcnt vmcnt(8)" ::: "memory");
      __builtin_amdgcn_s_barrier();
    } else if (ahead == 2) {
      asm volatile("s_waitcnt vmcnt(4)" ::: "memory");
      __builtin_amdgcn_s_barrier();
    } else if (ahead == 1) {
      asm volatile("s_waitcnt vmcnt(0)" ::: "memory");
      __builtin_amdgcn_s_barrier();
    }
  }
#undef STAGE

  // C/D layout: col = lane&15, row = (lane>>4)*4 + r  [measured m89/m91]
  const int crow = (lane >> 4) << 2;
  const int ccol = lane & 15;
#pragma unroll
  for (int i = 0; i < 8; i++) {
#pragma unroll
    for (int j = 0; j < 4; j++) {
      const int gm = tile_m + wr + i * 16 + crow;
      const int gn = tile_n + wc + j * 16 + ccol;
      const float bv = bias[gn];
#pragma unroll
      for (int r = 0; r < 4; r++) {
        float v = acc[i][j][r] + bv;
        v = fmaxf(v, 0.f);
        Cout[(size_t)(gm + r) * N + gn] = v;
      }
    }
  }
}

extern "C" void kernel_launch(void* const* d_in, const int* in_sizes, int n_in,
                              void* d_out, int out_size, void* d_ws, size_t ws_size,
                              hipStream_t stream) {
  const float* x        = (const float*)d_in[0];
  const float* W_q      = (const float*)d_in[1];
  const float* b_q      = (const float*)d_in[2];
  const float* beta_raw = (const float*)d_in[3];
  const float* W_fc     = (const float*)d_in[4];
  const float* b_fc     = (const float*)d_in[5];

  const int H = 1024;
  const int M = 2048 * 8;              // T*B = 16384 rows
  const size_t MH = (size_t)M * H;     // 16.7M elements

  char* ws = (char*)d_ws;
  u16* x_bf    = (u16*)ws;  ws += MH * 2;                   // 32 MB
  u16* m_loc   = (u16*)ws;  ws += MH * 2;                   // 32 MB
  u16* m_fix   = (u16*)ws;  ws += MH * 2;                   // 32 MB
  u16* wq_bf   = (u16*)ws;  ws += (size_t)H * H * 2;        // 2 MB
  u16* wfc_bf  = (u16*)ws;  ws += (size_t)H * H * 2;        // 2 MB
  float* beta  = (float*)ws; ws += 4096;
  float* bpow  = (float*)ws; ws += 33 * 1024 * 4;           // 132 KB
  float* carry = (float*)ws; ws += (size_t)64 * 8192 * 4;   // 2 MB

  prep_all<<<(int)(MH / 8 / 256), 256, 0, stream>>>(x, W_q, W_fc, beta_raw,
                                                    x_bf, wq_bf, wfc_bf, beta, bpow);

  // GEMM1 + full in-register segment-local scan (writes m_local + carry)
  gemm_scan<<<256, 512, 0, stream>>>(x_bf, wq_bf, b_q, m_loc, beta, carry, M, H, H);

  // fold + cross-segment fixup, single launch
  scanfix<<<2048, 256, 0, stream>>>(m_loc, carry, bpow, m_fix);

  // GEMM2: plain verified ring
  gemm_relu<<<256, 512, 0, stream>>>(m_fix, wfc_bf, b_fc, (float*)d_out, M, H, H);
}

// Round 12
// 238.050 us; speedup vs baseline: 1.0501x; 1.0501x over previous
//
#include <hip/hip_runtime.h>
#include <stdint.h>

typedef unsigned short u16;
typedef __bf16 bf16x8 __attribute__((ext_vector_type(8)));
typedef float f32x4 __attribute__((ext_vector_type(4)));

__device__ __forceinline__ u16 f2bf(float f) {
  union { float f; uint32_t u; } x; x.f = f;
  uint32_t u = x.u;
  u += 0x7fffu + ((u >> 16) & 1u);   // round-to-nearest-even
  return (u16)(u >> 16);
}
__device__ __forceinline__ float bf2f(uint32_t lo16) {
  union { uint32_t u; float f; } x; x.u = lo16 << 16; return x.f;
}

__device__ __forceinline__ void async_load16(const u16* g, u16* l) {
  __builtin_amdgcn_global_load_lds(
      (const __attribute__((address_space(1))) void*)g,
      (__attribute__((address_space(3))) void*)l,
      16, 0, 0);
}

// ---------------- prep_all: sigmoid(beta) + weight converts + x convert ----------------
__global__ __launch_bounds__(256) void prep_all(const float* __restrict__ x,
                                                const float* __restrict__ Wq,
                                                const float* __restrict__ Wfc,
                                                const float* __restrict__ braw,
                                                u16* __restrict__ xb,
                                                u16* __restrict__ wqb,
                                                u16* __restrict__ wfcb,
                                                float* __restrict__ beta) {
  int gid = blockIdx.x * 256 + threadIdx.x;
  if (gid < 1024) beta[gid] = 1.0f / (1.0f + expf(-braw[gid]));
  if (gid < 131072) {
    const int HH = 1024 * 1024;
    int i = gid * 16;
    const float* src = (i < HH) ? (Wq + i) : (Wfc + (i - HH));
    u16* dst = (i < HH) ? (wqb + i) : (wfcb + (i - HH));
#pragma unroll
    for (int c = 0; c < 4; c++) {
      float4 v = *(const float4*)(src + c * 4);
      ushort4 o = {f2bf(v.x), f2bf(v.y), f2bf(v.z), f2bf(v.w)};
      *(ushort4*)(dst + c * 4) = o;
    }
  }
  {
    int i = gid * 8;
    float4 a = *(const float4*)(x + i);
    float4 b = *(const float4*)(x + i + 4);
    ushort4 o0 = {f2bf(a.x), f2bf(a.y), f2bf(a.z), f2bf(a.w)};
    ushort4 o1 = {f2bf(b.x), f2bf(b.y), f2bf(b.z), f2bf(b.w)};
    *(ushort4*)(xb + i) = o0;
    *(ushort4*)(xb + i + 4) = o1;
  }
}

// ---------------- GEMM1: C = A*B^T + bias, bf16 out, fused segment-carry ----------------
// R4's harness-verified kernel (measured 45.5-48 us): 256x256 tile, BK=32,
// 4-deep LDS ring, counted vmcnt(8), XCD swizzle, CARRY epilogue.
__global__ __launch_bounds__(512, 2) void gemm_carry(const u16* __restrict__ A,
                                                     const u16* __restrict__ B,
                                                     const float* __restrict__ bias,
                                                     u16* __restrict__ Cout,
                                                     const float* __restrict__ beta_arr,
                                                     float* __restrict__ carry_out,
                                                     int M, int N, int K) {
  __shared__ u16 lds[4][2][256 * 32];  // 128 KiB ring

  const int tid  = threadIdx.x;
  const int lane = tid & 63;
  const int wid  = tid >> 6;
  const int wr   = (wid >> 2) * 128;
  const int wc   = (wid & 3) * 64;

  const int bid    = blockIdx.x;
  const int xcd    = bid & 7;
  const int idx    = bid >> 3;
  const int tile_m = ((xcd << 3) | (idx >> 2)) * 256;
  const int tile_n = (idx & 3) * 256;

  const int srow    = tid >> 2;
  const int schunk  = (tid & 3) ^ ((srow >> 1) & 3);
  const u16* gA = A + (size_t)(tile_m + srow) * K + schunk * 8;
  const u16* gB = B + (size_t)(tile_n + srow) * K + schunk * 8;
  const size_t half_stride = (size_t)128 * K;

#define STAGE(slot, kt)                                                   \
  do {                                                                    \
    const size_t k0 = (size_t)(kt) * 32;                                  \
    async_load16(gA + k0,               &lds[slot][0][wid * 512]);        \
    async_load16(gA + k0 + half_stride, &lds[slot][0][4096 + wid * 512]); \
    async_load16(gB + k0,               &lds[slot][1][wid * 512]);        \
    async_load16(gB + k0 + half_stride, &lds[slot][1][4096 + wid * 512]); \
  } while (0)

  f32x4 acc[8][4];
#pragma unroll
  for (int i = 0; i < 8; i++)
#pragma unroll
    for (int j = 0; j < 4; j++) acc[i][j] = (f32x4){0.f, 0.f, 0.f, 0.f};

  const int lrow = lane & 15;
  const int kq   = lane >> 4;
  const int kc   = (lrow >> 1) & 3;
  const int coff = ((kq ^ kc) << 3);

  const int NKT = K >> 5;  // 32

  STAGE(0, 0);
  if (NKT > 1) STAGE(1, 1);
  if (NKT > 2) STAGE(2, 2);
  if (NKT > 2)      asm volatile("s_waitcnt vmcnt(8)" ::: "memory");
  else if (NKT > 1) asm volatile("s_waitcnt vmcnt(4)" ::: "memory");
  else              asm volatile("s_waitcnt vmcnt(0)" ::: "memory");
  __builtin_amdgcn_s_barrier();

  for (int kt = 0; kt < NKT; ++kt) {
    const int slot = kt & 3;
    const u16* As = &lds[slot][0][0];
    const u16* Bs = &lds[slot][1][0];

    bf16x8 a[8], b[4];
#pragma unroll
    for (int i = 0; i < 8; i++)
      a[i] = *(const bf16x8*)&As[(wr + i * 16 + lrow) * 32 + coff];
#pragma unroll
    for (int j = 0; j < 4; j++)
      b[j] = *(const bf16x8*)&Bs[(wc + j * 16 + lrow) * 32 + coff];

    if (kt + 3 < NKT) STAGE((kt + 3) & 3, kt + 3);

    __builtin_amdgcn_s_setprio(1);
#pragma unroll
    for (int i = 0; i < 8; i++)
#pragma unroll
      for (int j = 0; j < 4; j++)
        acc[i][j] = __builtin_amdgcn_mfma_f32_16x16x32_bf16(a[i], b[j], acc[i][j], 0, 0, 0);
    __builtin_amdgcn_s_setprio(0);

    const int ahead = NKT - 1 - kt;
    if (ahead >= 3) {
      asm volatile("s_waitcnt vmcnt(8)" ::: "memory");
      __builtin_amdgcn_s_barrier();
    } else if (ahead == 2) {
      asm volatile("s_waitcnt vmcnt(4)" ::: "memory");
      __builtin_amdgcn_s_barrier();
    } else if (ahead == 1) {
      asm volatile("s_waitcnt vmcnt(0)" ::: "memory");
      __builtin_amdgcn_s_barrier();
    }
  }
#undef STAGE

  // C/D layout: col = lane&15, row = (lane>>4)*4 + r  [measured m89/m91]
  const int crow = (lane >> 4) << 2;
  const int ccol = lane & 15;
#pragma unroll
  for (int i = 0; i < 8; i++) {
#pragma unroll
    for (int j = 0; j < 4; j++) {
      const int gm = tile_m + wr + i * 16 + crow;
      const int gn = tile_n + wc + j * 16 + ccol;
      const float bv = bias[gn];
#pragma unroll
      for (int r = 0; r < 4; r++)
        Cout[(size_t)(gm + r) * N + gn] = f2bf(acc[i][j][r] + bv);
    }
  }

  // ---- fused scan_carry: carry[seg][b*1024+h] = sum_t beta_h^(31-t) q_t ----
  {
    float* ps = (float*)&lds[0][0][0];   // [2][8][256] f32 = 16 KB (ring slot 0)
    const int W   = wr >> 7;             // t-half (0: t 0..15, 1: t 16..31)
    const int kap = lane >> 5;           // t parity offset
#pragma unroll
    for (int j = 0; j < 4; j++) {
      const int gn = tile_n + wc + j * 16 + ccol;
      const float bv = bias[gn];
      const float b1 = beta_arr[gn];
      const float b2 = b1 * b1;
      const float b4 = b2 * b2, b8 = b4 * b4, b16 = b8 * b8;
      const float scale = W ? (kap ? 1.0f : b1) : (kap ? b16 : b16 * b1);
#pragma unroll
      for (int r = 0; r < 4; r++) {
        float Hn = acc[0][j][r] + bv;
#pragma unroll
        for (int i = 1; i < 8; i++) Hn = fmaf(b2, Hn, acc[i][j][r] + bv);
        float P = scale * Hn;
        P += __shfl_xor(P, 32);          // combine kappa halves (lane^32: same b,h)
        if (lane < 32) {
          const int bb = ((lane >> 4) << 2) + r;   // b index 0..7
          ps[W * 2048 + bb * 256 + wc + j * 16 + ccol] = P;
        }
      }
    }
    __syncthreads();
    {
      const int bb = tid >> 6;
      const int h4 = (tid & 63) << 2;
      float4 lo = *(float4*)&ps[bb * 256 + h4];
      float4 hi = *(float4*)&ps[2048 + bb * 256 + h4];
      float4 s  = make_float4(lo.x + hi.x, lo.y + hi.y, lo.z + hi.z, lo.w + hi.w);
      const int seg = tile_m >> 8;
      *(float4*)&carry_out[(size_t)seg * 8192 + bb * 1024 + tile_n + h4] = s;
    }
  }
}

// ---------------- scan_fuse (R4-verbatim): fold carries + rescan 32 q steps ----------
#define NCH 8192
#define SEG 32
#define NSEG 64

__global__ __launch_bounds__(256) void scan_fuse(const uint2* __restrict__ qb,
                                                 const float4* __restrict__ carry4,
                                                 const float* __restrict__ beta_arr,
                                                 uint2* __restrict__ mb) {
  const int tid = blockIdx.x * 256 + threadIdx.x;  // [0, 64*2048)
  const int seg = tid >> 11;
  const int cq  = tid & 2047;
  const int h0  = (cq * 4) & 1023;
  const float b0 = beta_arr[h0], b1 = beta_arr[h0 + 1];
  const float b2 = beta_arr[h0 + 2], b3 = beta_arr[h0 + 3];
  float s0 = b0, s1 = b1, s2 = b2, s3 = b3;
#pragma unroll
  for (int i = 0; i < 5; i++) { s0 *= s0; s1 *= s1; s2 *= s2; s3 *= s3; }  // beta^32
  float m0 = 0.f, m1 = 0.f, m2 = 0.f, m3 = 0.f;
  const float4* cp = carry4 + cq;
  for (int s = 0; s < seg; s++) {  // uniform per block
    float4 c = cp[(size_t)s * 2048];
    m0 = fmaf(s0, m0, c.x); m1 = fmaf(s1, m1, c.y);
    m2 = fmaf(s2, m2, c.z); m3 = fmaf(s3, m3, c.w);
  }
  const uint2* p = qb + (size_t)seg * SEG * 2048 + cq;
  uint2* o = mb + (size_t)seg * SEG * 2048 + cq;
#pragma unroll 8
  for (int t = 0; t < SEG; t++) {
    uint2 v = p[(size_t)t * 2048];
    m0 = fmaf(b0, m0, bf2f(v.x & 0xffffu));
    m1 = fmaf(b1, m1, bf2f(v.x >> 16));
    m2 = fmaf(b2, m2, bf2f(v.y & 0xffffu));
    m3 = fmaf(b3, m3, bf2f(v.y >> 16));
    uint2 w;
    w.x = (uint32_t)f2bf(m0) | ((uint32_t)f2bf(m1) << 16);
    w.y = (uint32_t)f2bf(m2) | ((uint32_t)f2bf(m3) << 16);
    o[(size_t)t * 2048] = w;
  }
}

// ---------------- GEMM2: relu(m Wfc^T + b_fc), HIGH-OCCUPANCY 128x128 ring ----------
// R12 experiment: same verified ring schedule / vmcnt ladder / swizzle family /
// R0-proven XCD map, but 128x128 tile, BK=32, 256 thr (4 waves 2x2, 64x64 each),
// LDS = 4 slots x (A 8KB + B 8KB) = 64 KiB -> 2 blocks/CU (vs 1 for the 256^2
// ring). All prior GEMMs: MfmaUtil~25 / HBM~25 / Occ~17 -> latency-bound with
// no co-resident block to fill barrier/DMA bubbles. Grid 1024 = 4 blocks/CU
// queued; 2 resident. Ring-safety proof identical to R1 (slot kt+3 last read
// at kt-1, collective barrier before overwrite; vmcnt(8) = 2 tiles in flight).
__global__ __launch_bounds__(256, 2) void gemm_relu128(const u16* __restrict__ A,
                                                       const u16* __restrict__ B,
                                                       const float* __restrict__ bias,
                                                       float* __restrict__ Cout,
                                                       int M, int N, int K) {
  __shared__ u16 lds[4][2][128 * 32];  // 64 KiB ring

  const int tid  = threadIdx.x;
  const int lane = tid & 63;
  const int wid  = tid >> 6;          // 0..3
  const int wr   = (wid >> 1) * 64;
  const int wc   = (wid & 1) * 64;

  // XCD map (R0-proven): 1024 blocks = 128 m-tiles x 8 n-tiles; xcd owns
  // m-tiles [16c,16c+16) x all 8 n.
  const int L  = blockIdx.x;
  const int xc = L & 7;
  const int k8 = L >> 3;
  const int tile_n = (k8 & 7) * 128;
  const int tile_m = ((xc << 4) | (k8 >> 3)) * 128;

  // staging: per issue, 256 thr x 16B = 64 rows x 64B; src chunk pre-swizzled.
  const int srow   = tid >> 2;              // 0..63
  const int schunk = (tid & 3) ^ ((srow >> 1) & 3);
  const u16* gA = A + (size_t)(tile_m + srow) * K + schunk * 8;
  const u16* gB = B + (size_t)(tile_n + srow) * K + schunk * 8;
  const size_t half_stride = (size_t)64 * K;  // rows 64..127

#define STAGE(slot, kt)                                                   \
  do {                                                                    \
    const size_t k0 = (size_t)(kt) * 32;                                  \
    async_load16(gA + k0,               &lds[slot][0][wid * 512]);        \
    async_load16(gA + k0 + half_stride, &lds[slot][0][2048 + wid * 512]); \
    async_load16(gB + k0,               &lds[slot][1][wid * 512]);        \
    async_load16(gB + k0 + half_stride, &lds[slot][1][2048 + wid * 512]); \
  } while (0)

  f32x4 acc[4][4];
#pragma unroll
  for (int i = 0; i < 4; i++)
#pragma unroll
    for (int j = 0; j < 4; j++) acc[i][j] = (f32x4){0.f, 0.f, 0.f, 0.f};

  const int lrow = lane & 15;
  const int kq   = lane >> 4;
  const int kc   = (lrow >> 1) & 3;
  const int coff = ((kq ^ kc) << 3);

  const int NKT = K >> 5;  // 32

  STAGE(0, 0);
  if (NKT > 1) STAGE(1, 1);
  if (NKT > 2) STAGE(2, 2);
  if (NKT > 2)      asm volatile("s_waitcnt vmcnt(8)" ::: "memory");
  else if (NKT > 1) asm volatile("s_waitcnt vmcnt(4)" ::: "memory");
  else              asm volatile("s_waitcnt vmcnt(0)" ::: "memory");
  __builtin_amdgcn_s_barrier();

  for (int kt = 0; kt < NKT; ++kt) {
    const int slot = kt & 3;
    const u16* As = &lds[slot][0][0];
    const u16* Bs = &lds[slot][1][0];

    bf16x8 a[4], b[4];
#pragma unroll
    for (int i = 0; i < 4; i++)
      a[i] = *(const bf16x8*)&As[(wr + i * 16 + lrow) * 32 + coff];
#pragma unroll
    for (int j = 0; j < 4; j++)
      b[j] = *(const bf16x8*)&Bs[(wc + j * 16 + lrow) * 32 + coff];

    if (kt + 3 < NKT) STAGE((kt + 3) & 3, kt + 3);

    __builtin_amdgcn_s_setprio(1);
#pragma unroll
    for (int i = 0; i < 4; i++)
#pragma unroll
      for (int j = 0; j < 4; j++)
        acc[i][j] = __builtin_amdgcn_mfma_f32_16x16x32_bf16(a[i], b[j], acc[i][j], 0, 0, 0);
    __builtin_amdgcn_s_setprio(0);

    const int ahead = NKT - 1 - kt;
    if (ahead >= 3) {
      asm volatile("s_waitcnt vmcnt(8)" ::: "memory");
      __builtin_amdgcn_s_barrier();
    } else if (ahead == 2) {
      asm volatile("s_waitcnt vmcnt(4)" ::: "memory");
      __builtin_amdgcn_s_barrier();
    } else if (ahead == 1) {
      asm volatile("s_waitcnt vmcnt(0)" ::: "memory");
      __builtin_amdgcn_s_barrier();
    }
  }
#undef STAGE

  // C/D layout: col = lane&15, row = (lane>>4)*4 + r  [measured m89/m91]
  const int crow = (lane >> 4) << 2;
  const int ccol = lane & 15;
#pragma unroll
  for (int i = 0; i < 4; i++) {
#pragma unroll
    for (int j = 0; j < 4; j++) {
      const int gm = tile_m + wr + i * 16 + crow;
      const int gn = tile_n + wc + j * 16 + ccol;
      const float bv = bias[gn];
#pragma unroll
      for (int r = 0; r < 4; r++) {
        float v = acc[i][j][r] + bv;
        v = fmaxf(v, 0.f);
        Cout[(size_t)(gm + r) * N + gn] = v;
      }
    }
  }
}

extern "C" void kernel_launch(void* const* d_in, const int* in_sizes, int n_in,
                              void* d_out, int out_size, void* d_ws, size_t ws_size,
                              hipStream_t stream) {
  const float* x        = (const float*)d_in[0];
  const float* W_q      = (const float*)d_in[1];
  const float* b_q      = (const float*)d_in[2];
  const float* beta_raw = (const float*)d_in[3];
  const float* W_fc     = (const float*)d_in[4];
  const float* b_fc     = (const float*)d_in[5];

  const int H = 1024;
  const int M = 2048 * 8;              // T*B = 16384 rows
  const size_t MH = (size_t)M * H;     // 16.7M elements

  char* ws = (char*)d_ws;
  u16* x_bf    = (u16*)ws;  ws += MH * 2;                   // 32 MB
  u16* q_bf    = (u16*)ws;  ws += MH * 2;                   // 32 MB
  u16* m_bf    = (u16*)ws;  ws += MH * 2;                   // 32 MB
  u16* wq_bf   = (u16*)ws;  ws += (size_t)H * H * 2;        // 2 MB
  u16* wfc_bf  = (u16*)ws;  ws += (size_t)H * H * 2;        // 2 MB
  float* beta  = (float*)ws; ws += 4096;
  float* carry = (float*)ws; ws += (size_t)NSEG * NCH * 4;  // 2 MB

  prep_all<<<(int)(MH / 8 / 256), 256, 0, stream>>>(x, W_q, W_fc, beta_raw,
                                                    x_bf, wq_bf, wfc_bf, beta);

  // GEMM1 + fused segment-carry epilogue (R4-verified)
  gemm_carry<<<256, 512, 0, stream>>>(x_bf, wq_bf, b_q, q_bf, beta, carry, M, H, H);

  // fold + rescan (R4-verified)
  scan_fuse<<<NSEG * (NCH / 4) / 256, 256, 0, stream>>>((const uint2*)q_bf,
                                                        (const float4*)carry, beta,
                                                        (uint2*)m_bf);

  // GEMM2: high-occupancy 128^2 ring (the isolated experiment)
  gemm_relu128<<<1024, 256, 0, stream>>>(m_bf, wfc_bf, b_fc, (float*)d_out, M, H, H);
}

// Round 13
// 233.841 us; speedup vs baseline: 1.0690x; 1.0180x over previous
//
#include <hip/hip_runtime.h>
#include <stdint.h>

typedef unsigned short u16;
typedef __bf16 bf16x8 __attribute__((ext_vector_type(8)));
typedef float f32x4 __attribute__((ext_vector_type(4)));

__device__ __forceinline__ u16 f2bf(float f) {
  union { float f; uint32_t u; } x; x.f = f;
  uint32_t u = x.u;
  u += 0x7fffu + ((u >> 16) & 1u);   // round-to-nearest-even
  return (u16)(u >> 16);
}
__device__ __forceinline__ float bf2f(uint32_t lo16) {
  union { uint32_t u; float f; } x; x.u = lo16 << 16; return x.f;
}

__device__ __forceinline__ void async_load16(const u16* g, u16* l) {
  __builtin_amdgcn_global_load_lds(
      (const __attribute__((address_space(1))) void*)g,
      (__attribute__((address_space(3))) void*)l,
      16, 0, 0);
}

// ---------------- prep_all: sigmoid(beta) + weight converts + x convert ----------------
__global__ __launch_bounds__(256) void prep_all(const float* __restrict__ x,
                                                const float* __restrict__ Wq,
                                                const float* __restrict__ Wfc,
                                                const float* __restrict__ braw,
                                                u16* __restrict__ xb,
                                                u16* __restrict__ wqb,
                                                u16* __restrict__ wfcb,
                                                float* __restrict__ beta) {
  int gid = blockIdx.x * 256 + threadIdx.x;
  if (gid < 1024) beta[gid] = 1.0f / (1.0f + expf(-braw[gid]));
  if (gid < 131072) {
    const int HH = 1024 * 1024;
    int i = gid * 16;
    const float* src = (i < HH) ? (Wq + i) : (Wfc + (i - HH));
    u16* dst = (i < HH) ? (wqb + i) : (wfcb + (i - HH));
#pragma unroll
    for (int c = 0; c < 4; c++) {
      float4 v = *(const float4*)(src + c * 4);
      ushort4 o = {f2bf(v.x), f2bf(v.y), f2bf(v.z), f2bf(v.w)};
      *(ushort4*)(dst + c * 4) = o;
    }
  }
  {
    int i = gid * 8;
    float4 a = *(const float4*)(x + i);
    float4 b = *(const float4*)(x + i + 4);
    ushort4 o0 = {f2bf(a.x), f2bf(a.y), f2bf(a.z), f2bf(a.w)};
    ushort4 o1 = {f2bf(b.x), f2bf(b.y), f2bf(b.z), f2bf(b.w)};
    *(ushort4*)(xb + i) = o0;
    *(ushort4*)(xb + i + 4) = o1;
  }
}

// ---------------- GEMM: C = A (MxK bf16) * B^T (NxK bf16) + bias ----------------
// R4's harness-verified best configuration (234.9 us total): 256x256 tile,
// BK=32, 8 waves (2Mx4N), 4-deep LDS ring (stage kt+3 while computing kt),
// counted vmcnt(8) (never 0 until the tail), XCD-aware block swizzle
// (FETCH 67.6 -> 24.6 MB, measured R2), XOR-chunk LDS swizzle (0 conflicts,
// measured every round). CARRY=1 (GEMM1): fused segment-carry epilogue
// computes carry[seg][b][h] = sum_t beta^(31-t) q_t from registers (fp32 q,
// more accurate than the old bf16 rescan pass) -- replaces the scan_carry
// dispatch. Ring-slot safety: slot (kt+3)&3 was last ds_read at iteration
// kt-1, whose reads complete before that iteration's end barrier (compiler
// lgkmcnt before MFMA), so the async overwrites can land any time after.
template <int RELU, int OUTBF, int CARRY>
__global__ __launch_bounds__(512, 2) void gemm256(const u16* __restrict__ A,
                                                  const u16* __restrict__ B,
                                                  const float* __restrict__ bias,
                                                  void* __restrict__ Cout,
                                                  const float* __restrict__ beta_arr,
                                                  float* __restrict__ carry_out,
                                                  int M, int N, int K) {
  __shared__ u16 lds[4][2][256 * 32];  // 128 KiB ring

  const int tid  = threadIdx.x;
  const int lane = tid & 63;
  const int wid  = tid >> 6;
  const int wr   = (wid >> 2) * 128;
  const int wc   = (wid & 3) * 64;

  // XCD-aware map: grid 256 = 64 m-tiles x 4 n-tiles; xcd = bid&7 owns
  // m-tiles [8c,8c+8) x all n (bijective, 256 % 8 == 0).
  const int bid    = blockIdx.x;
  const int xcd    = bid & 7;
  const int idx    = bid >> 3;
  const int tile_m = ((xcd << 3) | (idx >> 2)) * 256;
  const int tile_n = (idx & 3) * 256;

  // staging: per issue, 512 threads cover 128 rows x 4 chunks(16B); linear
  // LDS dest (global_load_lds constraint), source chunk pre-swizzled.
  const int srow    = tid >> 2;
  const int schunk  = (tid & 3) ^ ((srow >> 1) & 3);
  const u16* gA = A + (size_t)(tile_m + srow) * K + schunk * 8;
  const u16* gB = B + (size_t)(tile_n + srow) * K + schunk * 8;
  const size_t half_stride = (size_t)128 * K;

#define STAGE(slot, kt)                                                   \
  do {                                                                    \
    const size_t k0 = (size_t)(kt) * 32;                                  \
    async_load16(gA + k0,               &lds[slot][0][wid * 512]);        \
    async_load16(gA + k0 + half_stride, &lds[slot][0][4096 + wid * 512]); \
    async_load16(gB + k0,               &lds[slot][1][wid * 512]);        \
    async_load16(gB + k0 + half_stride, &lds[slot][1][4096 + wid * 512]); \
  } while (0)

  f32x4 acc[8][4];
#pragma unroll
  for (int i = 0; i < 8; i++)
#pragma unroll
    for (int j = 0; j < 4; j++) acc[i][j] = (f32x4){0.f, 0.f, 0.f, 0.f};

  const int lrow = lane & 15;
  const int kq   = lane >> 4;
  const int kc   = (lrow >> 1) & 3;        // read-side swizzle key
  const int coff = ((kq ^ kc) << 3);

  const int NKT = K >> 5;                  // 32

  STAGE(0, 0);
  if (NKT > 1) STAGE(1, 1);
  if (NKT > 2) STAGE(2, 2);
  if (NKT > 2)      asm volatile("s_waitcnt vmcnt(8)" ::: "memory");
  else if (NKT > 1) asm volatile("s_waitcnt vmcnt(4)" ::: "memory");
  else              asm volatile("s_waitcnt vmcnt(0)" ::: "memory");
  __builtin_amdgcn_s_barrier();

  for (int kt = 0; kt < NKT; ++kt) {
    const int slot = kt & 3;
    const u16* As = &lds[slot][0][0];
    const u16* Bs = &lds[slot][1][0];

    bf16x8 a[8], b[4];
#pragma unroll
    for (int i = 0; i < 8; i++)
      a[i] = *(const bf16x8*)&As[(wr + i * 16 + lrow) * 32 + coff];
#pragma unroll
    for (int j = 0; j < 4; j++)
      b[j] = *(const bf16x8*)&Bs[(wc + j * 16 + lrow) * 32 + coff];

    if (kt + 3 < NKT) STAGE((kt + 3) & 3, kt + 3);

    __builtin_amdgcn_s_setprio(1);
#pragma unroll
    for (int i = 0; i < 8; i++)
#pragma unroll
      for (int j = 0; j < 4; j++)
        acc[i][j] = __builtin_amdgcn_mfma_f32_16x16x32_bf16(a[i], b[j], acc[i][j], 0, 0, 0);
    __builtin_amdgcn_s_setprio(0);

    const int ahead = NKT - 1 - kt;
    if (ahead >= 3) {
      asm volatile("s_waitcnt vmcnt(8)" ::: "memory");
      __builtin_amdgcn_s_barrier();
    } else if (ahead == 2) {
      asm volatile("s_waitcnt vmcnt(4)" ::: "memory");
      __builtin_amdgcn_s_barrier();
    } else if (ahead == 1) {
      asm volatile("s_waitcnt vmcnt(0)" ::: "memory");
      __builtin_amdgcn_s_barrier();
    }
  }
#undef STAGE

  // C/D layout: col = lane&15, row = (lane>>4)*4 + r  [measured m89/m91]
  const int crow = (lane >> 4) << 2;
  const int ccol = lane & 15;
#pragma unroll
  for (int i = 0; i < 8; i++) {
#pragma unroll
    for (int j = 0; j < 4; j++) {
      const int gm = tile_m + wr + i * 16 + crow;
      const int gn = tile_n + wc + j * 16 + ccol;
      const float bv = bias[gn];
#pragma unroll
      for (int r = 0; r < 4; r++) {
        float v = acc[i][j][r] + bv;
        if (RELU) v = fmaxf(v, 0.f);
        if (OUTBF) ((u16*)Cout)[(size_t)(gm + r) * N + gn] = f2bf(v);
        else       ((float*)Cout)[(size_t)(gm + r) * N + gn] = v;
      }
    }
  }

  if (CARRY) {
    // ---- fused scan_carry: carry[seg][b*1024+h] = sum_t beta_h^(31-t) q_t ----
    // Lane algebra: row = wr + 16i + 4c4 + r (c4 = lane>>4) -> t = 2i + kappa
    // + 16W (kappa = lane>>5, W = wr>>7), b = (4c4+r)&7. Horner in beta^2
    // ascending i, scale beta^(17-kap-16W); kappa halves via shfl_xor(32);
    // W halves via 16 KB LDS ps[2][8][256] (ring slot 0; last ds_read >= 2
    // barriers earlier) + one __syncthreads.
    float* ps = (float*)&lds[0][0][0];
    const int W   = wr >> 7;
    const int kap = lane >> 5;
#pragma unroll
    for (int j = 0; j < 4; j++) {
      const int gn = tile_n + wc + j * 16 + ccol;
      const float bv = bias[gn];
      const float b1 = beta_arr[gn];
      const float b2 = b1 * b1;
      const float b4 = b2 * b2, b8 = b4 * b4, b16 = b8 * b8;
      const float scale = W ? (kap ? 1.0f : b1) : (kap ? b16 : b16 * b1);
#pragma unroll
      for (int r = 0; r < 4; r++) {
        float Hn = acc[0][j][r] + bv;
#pragma unroll
        for (int i = 1; i < 8; i++) Hn = fmaf(b2, Hn, acc[i][j][r] + bv);
        float P = scale * Hn;
        P += __shfl_xor(P, 32);          // combine kappa halves (lane^32: same b,h)
        if (lane < 32) {
          const int bb = ((lane >> 4) << 2) + r;
          ps[W * 2048 + bb * 256 + wc + j * 16 + ccol] = P;
        }
      }
    }
    __syncthreads();
    {
      const int bb = tid >> 6;
      const int h4 = (tid & 63) << 2;
      float4 lo = *(float4*)&ps[bb * 256 + h4];
      float4 hi = *(float4*)&ps[2048 + bb * 256 + h4];
      float4 s  = make_float4(lo.x + hi.x, lo.y + hi.y, lo.z + hi.z, lo.w + hi.w);
      const int seg = tile_m >> 8;
      *(float4*)&carry_out[(size_t)seg * 8192 + bb * 1024 + tile_n + h4] = s;
    }
  }
}

// ---------------- scan: m_t = beta*m_{t-1} + q_t over T=2048, channels = B*H = 8192 ----
#define NCH 8192
#define SEG 32
#define NSEG 64

// fused fold + rescan: F = Horner-fold of the seg upstream carries with ratio
// beta^32 (2 MB, L2-resident), then rescan 32 q steps from m=F, emit bf16 m.
__global__ __launch_bounds__(256) void scan_fuse(const uint2* __restrict__ qb,
                                                 const float4* __restrict__ carry4,
                                                 const float* __restrict__ beta_arr,
                                                 uint2* __restrict__ mb) {
  const int tid = blockIdx.x * 256 + threadIdx.x;  // [0, 64*2048)
  const int seg = tid >> 11;
  const int cq  = tid & 2047;
  const int h0  = (cq * 4) & 1023;
  const float b0 = beta_arr[h0], b1 = beta_arr[h0 + 1];
  const float b2 = beta_arr[h0 + 2], b3 = beta_arr[h0 + 3];
  float s0 = b0, s1 = b1, s2 = b2, s3 = b3;
#pragma unroll
  for (int i = 0; i < 5; i++) { s0 *= s0; s1 *= s1; s2 *= s2; s3 *= s3; }  // beta^32
  float m0 = 0.f, m1 = 0.f, m2 = 0.f, m3 = 0.f;
  const float4* cp = carry4 + cq;
  for (int s = 0; s < seg; s++) {  // uniform per block
    float4 c = cp[(size_t)s * 2048];
    m0 = fmaf(s0, m0, c.x); m1 = fmaf(s1, m1, c.y);
    m2 = fmaf(s2, m2, c.z); m3 = fmaf(s3, m3, c.w);
  }
  const uint2* p = qb + (size_t)seg * SEG * 2048 + cq;
  uint2* o = mb + (size_t)seg * SEG * 2048 + cq;
#pragma unroll 8
  for (int t = 0; t < SEG; t++) {
    uint2 v = p[(size_t)t * 2048];
    m0 = fmaf(b0, m0, bf2f(v.x & 0xffffu));
    m1 = fmaf(b1, m1, bf2f(v.x >> 16));
    m2 = fmaf(b2, m2, bf2f(v.y & 0xffffu));
    m3 = fmaf(b3, m3, bf2f(v.y >> 16));
    uint2 w;
    w.x = (uint32_t)f2bf(m0) | ((uint32_t)f2bf(m1) << 16);
    w.y = (uint32_t)f2bf(m2) | ((uint32_t)f2bf(m3) << 16);
    o[(size_t)t * 2048] = w;
  }
}

extern "C" void kernel_launch(void* const* d_in, const int* in_sizes, int n_in,
                              void* d_out, int out_size, void* d_ws, size_t ws_size,
                              hipStream_t stream) {
  const float* x        = (const float*)d_in[0];
  const float* W_q      = (const float*)d_in[1];
  const float* b_q      = (const float*)d_in[2];
  const float* beta_raw = (const float*)d_in[3];
  const float* W_fc     = (const float*)d_in[4];
  const float* b_fc     = (const float*)d_in[5];

  const int H = 1024;
  const int M = 2048 * 8;              // T*B = 16384 rows
  const size_t MH = (size_t)M * H;     // 16.7M elements

  char* ws = (char*)d_ws;
  u16* x_bf    = (u16*)ws;  ws += MH * 2;                   // 32 MB
  u16* q_bf    = (u16*)ws;  ws += MH * 2;                   // 32 MB
  u16* m_bf    = (u16*)ws;  ws += MH * 2;                   // 32 MB
  u16* wq_bf   = (u16*)ws;  ws += (size_t)H * H * 2;        // 2 MB
  u16* wfc_bf  = (u16*)ws;  ws += (size_t)H * H * 2;        // 2 MB
  float* beta  = (float*)ws; ws += 4096;
  float* carry = (float*)ws; ws += (size_t)NSEG * NCH * 4;  // 2 MB

  prep_all<<<(int)(MH / 8 / 256), 256, 0, stream>>>(x, W_q, W_fc, beta_raw,
                                                    x_bf, wq_bf, wfc_bf, beta);

  // GEMM1 + fused segment-carry epilogue (replaces the scan_carry dispatch)
  gemm256<0, 1, 1><<<256, 512, 0, stream>>>(x_bf, wq_bf, b_q, q_bf,
                                            beta, carry, M, H, H);

  scan_fuse<<<NSEG * (NCH / 4) / 256, 256, 0, stream>>>((const uint2*)q_bf,
                                                        (const float4*)carry, beta,
                                                        (uint2*)m_bf);

  gemm256<1, 0, 0><<<256, 512, 0, stream>>>(m_bf, wfc_bf, b_fc, d_out,
                                            beta, nullptr, M, H, H);
}